// Round 1
// baseline (314.835 us; speedup 1.0000x reference)
//
#include <hip/hip_runtime.h>

// VectorQuantizer: z_e [32,256,32,32] fp32, weight [1024,256] fp32
// out: z_q [32,256,32,32] fp32  ++  indices [32,32,32] stored as float
//
// argmin_k ||z_hat - w_hat_k||^2 == argmax_k <z, w_hat_k>  (z-normalization is
// a positive per-pixel scalar -> argmax invariant), so only the codebook is
// normalized. z_q gathers normalized codebook rows -> exact.

#define C_DIM 256
#define K_CODES 1024
#define HW 1024          // 32*32
#define NPIX 32768       // 32 * 1024
#define BM 64            // pixels per block tile
#define BN 256           // codes per block tile
#define BK 16            // k-chunk

// ---------------- kernel 1: normalize codebook (+ transpose copy) -----------
__global__ __launch_bounds__(256) void vq_norm_w(const float* __restrict__ w,
                                                 float* __restrict__ w_n,
                                                 float* __restrict__ w_nT) {
    const int row = blockIdx.x;        // 0..1023
    const int t   = threadIdx.x;       // 0..255
    float x = w[row * C_DIM + t];
    float s = x * x;
    // wave-64 reduce
    #pragma unroll
    for (int off = 32; off > 0; off >>= 1) s += __shfl_down(s, off, 64);
    __shared__ float wsum[4];
    if ((t & 63) == 0) wsum[t >> 6] = s;
    __syncthreads();
    float tot = wsum[0] + wsum[1] + wsum[2] + wsum[3];
    float inv = 1.0f / fmaxf(sqrtf(tot), 1e-12f);
    float y = x * inv;
    w_n[row * C_DIM + t]  = y;
    w_nT[t * K_CODES + row] = y;       // scattered, tiny kernel, fine
}

// ---------------- kernel 2: fused GEMM + per-tile argmax --------------------
// grid (512 pixel tiles, 4 code tiles), 256 threads.
// thread tile: 8 pixels (ty*8 .. +7) x 8 codes ({tx*4..+3} U {128+tx*4..+3})
__global__ __launch_bounds__(256) void vq_gemm_argmax(
        const float* __restrict__ z,    // [32][256][1024]
        const float* __restrict__ wT,   // [256][1024] normalized, transposed
        float* __restrict__ cand_val,   // [512][4][64]
        int*   __restrict__ cand_idx) { // [512][4][64]
    __shared__ float As[BK][BM];        // 4 KB
    __shared__ float Bs[BK][BN];        // 16 KB
    __shared__ float rv[BM][32];        // 8 KB  (reduction)
    __shared__ int   ri[BM][32];        // 8 KB

    const int tid = threadIdx.x;
    const int pt  = blockIdx.x;         // pixel tile
    const int ct  = blockIdx.y;         // code tile
    const int tx  = tid & 31;
    const int ty  = tid >> 5;           // 0..7

    const int n0 = pt * BM;             // first global pixel of tile
    const int b  = n0 >> 10;
    const int p0 = n0 & 1023;
    const float* zb = z  + (size_t)b * (C_DIM * HW) + p0;  // + c*1024 + i
    const float* wb = wT + ct * BN;                        // + c*1024 + j

    // staging assignments (all float4-coalesced)
    const int a_kk = tid >> 4;          // 0..15
    const int a_i4 = (tid & 15) * 4;    // 0..60
    const int b_kk = (tid >> 6) * 4;    // 0,4,8,12
    const int b_c4 = (tid & 63) * 4;    // 0..252

    float acc[8][8];
    #pragma unroll
    for (int i = 0; i < 8; i++)
        #pragma unroll
        for (int j = 0; j < 8; j++) acc[i][j] = 0.0f;

    for (int k0 = 0; k0 < C_DIM; k0 += BK) {
        float4 av = *(const float4*)(zb + (size_t)(k0 + a_kk) * HW + a_i4);
        float4 bv[4];
        #pragma unroll
        for (int j = 0; j < 4; j++)
            bv[j] = *(const float4*)(wb + (size_t)(k0 + b_kk + j) * K_CODES + b_c4);
        __syncthreads();                 // previous iteration's reads done
        *(float4*)&As[a_kk][a_i4] = av;
        #pragma unroll
        for (int j = 0; j < 4; j++)
            *(float4*)&Bs[b_kk + j][b_c4] = bv[j];
        __syncthreads();
        #pragma unroll
        for (int kk = 0; kk < BK; kk++) {
            float a0[8], b0[8];
            *(float4*)&a0[0] = *(const float4*)&As[kk][ty * 8];
            *(float4*)&a0[4] = *(const float4*)&As[kk][ty * 8 + 4];
            *(float4*)&b0[0] = *(const float4*)&Bs[kk][tx * 4];
            *(float4*)&b0[4] = *(const float4*)&Bs[kk][128 + tx * 4];
            #pragma unroll
            for (int i = 0; i < 8; i++)
                #pragma unroll
                for (int j = 0; j < 8; j++)
                    acc[i][j] = fmaf(a0[i], b0[j], acc[i][j]);
        }
    }

    // thread-local argmax over its 8 codes, per pixel (tie -> smaller index,
    // matching argmin-first semantics)
    #pragma unroll
    for (int i = 0; i < 8; i++) {
        float bvv = acc[i][0];
        int   bii = tx * 4;
        #pragma unroll
        for (int j = 1; j < 8; j++) {
            int c = (j < 4) ? (tx * 4 + j) : (128 + tx * 4 + (j - 4));
            float v = acc[i][j];
            if (v > bvv || (v == bvv && c < bii)) { bvv = v; bii = c; }
        }
        rv[ty * 8 + i][tx] = bvv;
        ri[ty * 8 + i][tx] = bii;
    }
    __syncthreads();
    if (tid < BM) {
        float bvv = rv[tid][0];
        int   bii = ri[tid][0];
        for (int t2 = 1; t2 < 32; t2++) {
            float v = rv[tid][t2];
            int   c = ri[tid][t2];
            if (v > bvv || (v == bvv && c < bii)) { bvv = v; bii = c; }
        }
        int slot = (pt * 4 + ct) * BM + tid;
        cand_val[slot] = bvv;
        cand_idx[slot] = ct * BN + bii;
    }
}

// ---------------- kernel 3: reduce candidates + gather ----------------------
__global__ __launch_bounds__(256) void vq_finalize(
        const float* __restrict__ cand_val,
        const int*   __restrict__ cand_idx,
        const float* __restrict__ w_n,
        float* __restrict__ zq,          // [32][256][1024]
        float* __restrict__ idx_out) {   // [32768] as float
    const int n = blockIdx.x * 256 + threadIdx.x;   // 0..32767
    const int pt  = n >> 6;
    const int pix = n & 63;
    const int base = pt * 256 + pix;                 // (pt*4 + 0)*64 + pix
    float bvv = cand_val[base];
    int   bii = cand_idx[base];
    #pragma unroll
    for (int ct = 1; ct < 4; ct++) {
        float v = cand_val[base + ct * 64];
        int   c = cand_idx[base + ct * 64];
        if (v > bvv || (v == bvv && c < bii)) { bvv = v; bii = c; }
    }
    idx_out[n] = (float)bii;
    const int b = n >> 10;
    const int p = n & 1023;
    float* zqb = zq + (size_t)b * (C_DIM * HW) + p;
    const float* wr = w_n + (size_t)bii * C_DIM;
    #pragma unroll 4
    for (int c = 0; c < C_DIM; c += 4) {
        float4 wv = *(const float4*)(wr + c);
        zqb[(size_t)(c + 0) * HW] = wv.x;
        zqb[(size_t)(c + 1) * HW] = wv.y;
        zqb[(size_t)(c + 2) * HW] = wv.z;
        zqb[(size_t)(c + 3) * HW] = wv.w;
    }
}

// ---------------- launcher --------------------------------------------------
extern "C" void kernel_launch(void* const* d_in, const int* in_sizes, int n_in,
                              void* d_out, int out_size, void* d_ws, size_t ws_size,
                              hipStream_t stream) {
    const float* z = (const float*)d_in[0];   // 32*256*32*32
    const float* w = (const float*)d_in[1];   // 1024*256
    float* out     = (float*)d_out;           // z_q (8388608) ++ indices (32768)

    float* ws    = (float*)d_ws;
    float* w_n   = ws;                         // 262144 floats (1 MB)
    float* w_nT  = ws + 262144;                // 262144 floats (1 MB)
    float* cval  = ws + 524288;                // 131072 floats (0.5 MB)
    int*   cidx  = (int*)(ws + 655360);        // 131072 ints   (0.5 MB)

    vq_norm_w<<<K_CODES, 256, 0, stream>>>(w, w_n, w_nT);
    vq_gemm_argmax<<<dim3(NPIX / BM, K_CODES / BN), 256, 0, stream>>>(z, w_nT, cval, cidx);
    vq_finalize<<<NPIX / 256, 256, 0, stream>>>(cval, cidx, w_n, out, out + 8388608);
}

// Round 2
// 191.743 us; speedup vs baseline: 1.6420x; 1.6420x over previous
//
#include <hip/hip_runtime.h>

// VectorQuantizer via f16-split-3 MFMA (Markidis fp32 emulation):
//   x = hi + lo*2^-11,  hi = f16(x), lo = f16((x-hi)*2048)   (scaled -> normal range)
//   dot = [hi_a.hi_b] + ([hi_a.lo_b] + [lo_a.hi_b]) * 2^-11  (lo.lo ~2^-22, omitted)
// argmin_k ||z_hat - w_hat_k|| == argmax_k <z, w_hat_k>  -> only codebook normalized.

typedef _Float16 half8 __attribute__((ext_vector_type(8)));
typedef float floatx4 __attribute__((ext_vector_type(4)));

#define C_DIM 256
#define K_CODES 1024
#define HW 1024
#define NPIX 32768
#define LO_SCALE 2048.0f
#define LO_INV   (1.0f/2048.0f)
#define LDS_STRIDE 40            // 32 f16 + 8 pad -> row stride 80 B = 20 banks (2-way only)

// ---------------- kernel 1: normalize codebook + f16 split ------------------
__global__ __launch_bounds__(256) void vq_norm_w(const float* __restrict__ w,
                                                 float* __restrict__ w_n,
                                                 _Float16* __restrict__ wh,
                                                 _Float16* __restrict__ wl) {
    const int row = blockIdx.x;        // 0..1023
    const int t   = threadIdx.x;       // 0..255
    float x = w[row * C_DIM + t];
    float s = x * x;
    #pragma unroll
    for (int off = 32; off > 0; off >>= 1) s += __shfl_down(s, off, 64);
    __shared__ float wsum[4];
    if ((t & 63) == 0) wsum[t >> 6] = s;
    __syncthreads();
    float tot = wsum[0] + wsum[1] + wsum[2] + wsum[3];
    float inv = 1.0f / fmaxf(sqrtf(tot), 1e-12f);
    float y = x * inv;
    w_n[row * C_DIM + t] = y;
    _Float16 hi = (_Float16)y;
    wh[row * C_DIM + t] = hi;
    wl[row * C_DIM + t] = (_Float16)((y - (float)hi) * LO_SCALE);
}

// ---------------- kernel 2: transpose + f16-split z -------------------------
// z [32][256][1024] -> zh/zl [32768 pixels][256 c]
__global__ __launch_bounds__(256) void vq_split_z(const float* __restrict__ z,
                                                  _Float16* __restrict__ zh,
                                                  _Float16* __restrict__ zl) {
    __shared__ float tile[64][65];
    const int t  = threadIdx.x;
    const int pt = blockIdx.x;         // 16 pixel tiles (of 64)
    const int ct = blockIdx.y;         // 4 channel tiles (of 64)
    const int b  = blockIdx.z;         // 32 batches
    const float* zb = z + ((size_t)b * C_DIM + ct * 64) * HW + pt * 64;
    const int rr = t >> 4, pp = (t & 15) * 4;
    #pragma unroll
    for (int pass = 0; pass < 4; pass++) {
        float4 v = *(const float4*)(zb + (size_t)(pass * 16 + rr) * HW + pp);
        *(float4*)&tile[pass * 16 + rr][pp] = v;
    }
    __syncthreads();
    const int pl = t >> 2;
    const size_t pix = (size_t)b * HW + pt * 64 + pl;
    #pragma unroll
    for (int pass = 0; pass < 2; pass++) {
        const int c0 = ((t & 3) + 4 * pass) * 8;
        half8 hi, lo;
        #pragma unroll
        for (int j = 0; j < 8; j++) {
            float x = tile[c0 + j][pl];
            _Float16 h = (_Float16)x;
            hi[j] = h;
            lo[j] = (_Float16)((x - (float)h) * LO_SCALE);
        }
        *(half8*)(zh + pix * C_DIM + ct * 64 + c0) = hi;
        *(half8*)(zl + pix * C_DIM + ct * 64 + c0) = lo;
    }
}

// ---------------- kernel 3: MFMA GEMM + fused argmax ------------------------
// grid (256 m-tiles, 8 n-tiles), 256 thr = 4 waves in 2x2; wave tile 64x64.
__global__ __launch_bounds__(256, 2) void vq_gemm(
        const _Float16* __restrict__ zh, const _Float16* __restrict__ zl,
        const _Float16* __restrict__ wh, const _Float16* __restrict__ wl,
        float* __restrict__ cand_val, int* __restrict__ cand_idx) {
    __shared__ _Float16 Ah[128 * LDS_STRIDE];   // 10 KB each
    __shared__ _Float16 Al[128 * LDS_STRIDE];
    __shared__ _Float16 Bh[128 * LDS_STRIDE];
    __shared__ _Float16 Bl[128 * LDS_STRIDE];
    __shared__ float red_v[128][2];
    __shared__ int   red_i[128][2];

    const int tid  = threadIdx.x;
    const int lane = tid & 63, wave = tid >> 6;
    const int wm = wave >> 1, wn = wave & 1;
    const int quad = lane >> 4, l15 = lane & 15;
    const int m0 = blockIdx.x * 128, n0 = blockIdx.y * 128;

    // staging: 512 16B-chunks per plane, 2 per thread
    const int sr  = tid >> 2;           // rows 0..63
    const int sc  = (tid & 3) * 8;      // f16 col 0,8,16,24
    const int sr1 = sr + 64;

    floatx4 acc_h[4][4], acc_x[4][4];
    #pragma unroll
    for (int i = 0; i < 4; i++)
        #pragma unroll
        for (int j = 0; j < 4; j++) {
            acc_h[i][j] = (floatx4){0.f, 0.f, 0.f, 0.f};
            acc_x[i][j] = (floatx4){0.f, 0.f, 0.f, 0.f};
        }

    const int aoff = (wm * 64 + l15) * LDS_STRIDE + quad * 8;
    const int boff = (wn * 64 + l15) * LDS_STRIDE + quad * 8;
    const int l0 = sr  * LDS_STRIDE + sc;
    const int l1 = sr1 * LDS_STRIDE + sc;

    for (int kt = 0; kt < 8; kt++) {
        const int k0 = kt * 32;
        const size_t ga0 = (size_t)(m0 + sr ) * C_DIM + k0 + sc;
        const size_t ga1 = (size_t)(m0 + sr1) * C_DIM + k0 + sc;
        const size_t gb0 = (size_t)(n0 + sr ) * C_DIM + k0 + sc;
        const size_t gb1 = (size_t)(n0 + sr1) * C_DIM + k0 + sc;
        uint4 vah0 = *(const uint4*)(zh + ga0);
        uint4 vah1 = *(const uint4*)(zh + ga1);
        uint4 val0 = *(const uint4*)(zl + ga0);
        uint4 val1 = *(const uint4*)(zl + ga1);
        uint4 vbh0 = *(const uint4*)(wh + gb0);
        uint4 vbh1 = *(const uint4*)(wh + gb1);
        uint4 vbl0 = *(const uint4*)(wl + gb0);
        uint4 vbl1 = *(const uint4*)(wl + gb1);
        __syncthreads();                      // previous iter's frag reads done
        *(uint4*)&Ah[l0] = vah0;  *(uint4*)&Ah[l1] = vah1;
        *(uint4*)&Al[l0] = val0;  *(uint4*)&Al[l1] = val1;
        *(uint4*)&Bh[l0] = vbh0;  *(uint4*)&Bh[l1] = vbh1;
        *(uint4*)&Bl[l0] = vbl0;  *(uint4*)&Bl[l1] = vbl1;
        __syncthreads();

        half8 ah[4], al[4], bh[4], bl[4];
        #pragma unroll
        for (int i = 0; i < 4; i++) {
            ah[i] = *(const half8*)&Ah[aoff + i * 16 * LDS_STRIDE];
            al[i] = *(const half8*)&Al[aoff + i * 16 * LDS_STRIDE];
            bh[i] = *(const half8*)&Bh[boff + i * 16 * LDS_STRIDE];
            bl[i] = *(const half8*)&Bl[boff + i * 16 * LDS_STRIDE];
        }
        #pragma unroll
        for (int mi = 0; mi < 4; mi++)
            #pragma unroll
            for (int ni = 0; ni < 4; ni++) {
                acc_h[mi][ni] = __builtin_amdgcn_mfma_f32_16x16x32_f16(ah[mi], bh[ni], acc_h[mi][ni], 0, 0, 0);
                acc_x[mi][ni] = __builtin_amdgcn_mfma_f32_16x16x32_f16(ah[mi], bl[ni], acc_x[mi][ni], 0, 0, 0);
                acc_x[mi][ni] = __builtin_amdgcn_mfma_f32_16x16x32_f16(al[mi], bh[ni], acc_x[mi][ni], 0, 0, 0);
            }
    }

    // epilogue: per-lane best over ni, shfl-reduce over the 16 lanes of each quad
    #pragma unroll
    for (int mi = 0; mi < 4; mi++) {
        #pragma unroll
        for (int r = 0; r < 4; r++) {
            float bv = -__builtin_inff();
            int   bi = 0x7fffffff;
            #pragma unroll
            for (int ni = 0; ni < 4; ni++) {
                float v = acc_h[mi][ni][r] + acc_x[mi][ni][r] * LO_INV;
                int  ci = n0 + wn * 64 + ni * 16 + l15;
                if (v > bv || (v == bv && ci < bi)) { bv = v; bi = ci; }
            }
            #pragma unroll
            for (int mk = 8; mk; mk >>= 1) {
                float ov = __shfl_xor(bv, mk, 16);
                int   oi = __shfl_xor(bi, mk, 16);
                if (ov > bv || (ov == bv && oi < bi)) { bv = ov; bi = oi; }
            }
            if (l15 == 0) {
                int row = wm * 64 + mi * 16 + quad * 4 + r;  // C/D: row=(lane>>4)*4+reg
                red_v[row][wn] = bv;
                red_i[row][wn] = bi;
            }
        }
    }
    __syncthreads();
    if (tid < 128) {
        float bv = red_v[tid][0]; int bi = red_i[tid][0];
        float v2 = red_v[tid][1]; int i2 = red_i[tid][1];
        if (v2 > bv || (v2 == bv && i2 < bi)) { bv = v2; bi = i2; }
        const int pix = m0 + tid;
        cand_val[(size_t)pix * 8 + blockIdx.y] = bv;
        cand_idx[(size_t)pix * 8 + blockIdx.y] = bi;
    }
}

// ---------------- kernel 4: reduce 8 candidates + gather --------------------
__global__ __launch_bounds__(256) void vq_finalize(
        const float* __restrict__ cand_val,
        const int*   __restrict__ cand_idx,
        const float* __restrict__ w_n,
        float* __restrict__ zq,          // [32][256][1024]
        float* __restrict__ idx_out) {   // [32768] as float
    const int n = blockIdx.x * 256 + threadIdx.x;
    const size_t base = (size_t)n * 8;
    float bv = cand_val[base];
    int   bi = cand_idx[base];
    #pragma unroll
    for (int t = 1; t < 8; t++) {
        float v = cand_val[base + t];
        int   c = cand_idx[base + t];
        if (v > bv || (v == bv && c < bi)) { bv = v; bi = c; }
    }
    idx_out[n] = (float)bi;
    const int b = n >> 10;
    const int p = n & 1023;
    float* zqb = zq + (size_t)b * (C_DIM * HW) + p;
    const float* wr = w_n + (size_t)bi * C_DIM;
    #pragma unroll 4
    for (int c = 0; c < C_DIM; c += 4) {
        float4 wv = *(const float4*)(wr + c);
        zqb[(size_t)(c + 0) * HW] = wv.x;
        zqb[(size_t)(c + 1) * HW] = wv.y;
        zqb[(size_t)(c + 2) * HW] = wv.z;
        zqb[(size_t)(c + 3) * HW] = wv.w;
    }
}

// ---------------- launcher --------------------------------------------------
extern "C" void kernel_launch(void* const* d_in, const int* in_sizes, int n_in,
                              void* d_out, int out_size, void* d_ws, size_t ws_size,
                              hipStream_t stream) {
    const float* z = (const float*)d_in[0];   // 32*256*32*32
    const float* w = (const float*)d_in[1];   // 1024*256
    float* out     = (float*)d_out;           // z_q (8388608) ++ indices (32768)

    char* ws = (char*)d_ws;
    float*    w_n  = (float*)(ws);                       //  0     .. 1 MB
    _Float16* wh   = (_Float16*)(ws + (1u << 20));       //  1 MB  .. 1.5 MB
    _Float16* wl   = (_Float16*)(ws + (3u << 19));       //  1.5   .. 2 MB
    _Float16* zh   = (_Float16*)(ws + (2u << 20));       //  2 MB  .. 18 MB
    _Float16* zl   = (_Float16*)(ws + 18874368u);        // 18 MB  .. 34 MB
    float*    cval = (float*)(ws + 35651584u);           // 34 MB  .. 35 MB
    int*      cidx = (int*)(ws + 36700160u);             // 35 MB  .. 36 MB

    vq_norm_w<<<K_CODES, 256, 0, stream>>>(w, w_n, wh, wl);
    vq_split_z<<<dim3(16, 4, 32), 256, 0, stream>>>(z, zh, zl);
    vq_gemm<<<dim3(NPIX / 128, K_CODES / 128), 256, 0, stream>>>(zh, zl, wh, wl, cval, cidx);
    vq_finalize<<<NPIX / 256, 256, 0, stream>>>(cval, cidx, w_n, out, out + 8388608);
}